// Round 1
// baseline (1544.096 us; speedup 1.0000x reference)
//
#include <hip/hip_runtime.h>

// ---------------- problem constants ----------------
#define NB   16
#define HW   4096          // 64*64
#define NPIX 65536         // NB*HW

// ---------------- ws layout (in floats) ----------------
constexpr size_t SIGMA_OFF = 0;          // 4 floats
constexpr size_t WT_C1 = 256;            // 576x128
constexpr size_t WT_C2 = WT_C1 + 73728;  // 1152x64
constexpr size_t WT_F1 = WT_C2 + 73728;  // 1152x128
constexpr size_t WT_F2 = WT_F1 + 147456; // 1152x64
constexpr size_t WT_Q1 = WT_F2 + 73728;  // 64x128
constexpr size_t WT_K1 = WT_Q1 + 8192;
constexpr size_t WT_V1 = WT_K1 + 8192;
constexpr size_t WT_S1 = WT_V1 + 8192;
constexpr size_t WT_Q2 = WT_S1 + 8192;   // 128x64
constexpr size_t WT_K2 = WT_Q2 + 8192;
constexpr size_t WT_V2 = WT_K2 + 8192;
constexpr size_t WT_S2 = WT_V2 + 8192;

constexpr size_t BUFA  = 524288;             // 8.4M floats: Q1 -> y1
constexpr size_t BUFB  = BUFA + 8388608;     // K1 -> t (conv3 out)
constexpr size_t BUFC  = BUFB + 8388608;     // V1 -> Q2
constexpr size_t BUFC2 = BUFC + 4194304;     //       K2 (2nd half of V1 region)
constexpr size_t BUFD  = BUFC + 8388608;     // S1 -> h
constexpr size_t BUFE  = BUFD + 8388608;     // V2 -> x1 (4.2M)
constexpr size_t BUFF  = BUFE + 4194304;     // S2 -> x2 (4.2M)

__device__ __forceinline__ float gelu_f(float v) {
    return 0.5f * v * (1.0f + erff(v * 0.70710678118654752f));
}

// ---------------- block reduction ----------------
__device__ float block_sum(float vv, float* red) {
    #pragma unroll
    for (int m = 1; m < 64; m <<= 1) vv += __shfl_xor(vv, m);
    int tid = threadIdx.x;
    __syncthreads();
    if ((tid & 63) == 0) red[tid >> 6] = vv;
    __syncthreads();
    return red[0] + red[1] + red[2] + red[3];
}

// ---------------- spectral norm sigma (one block per conv weight) ----------------
__global__ __launch_bounds__(256)
void sigma_kernel(const float* __restrict__ cW1, const float* __restrict__ cW2,
                  const float* __restrict__ fW1, const float* __restrict__ fW2,
                  float* __restrict__ sig) {
    __shared__ float u[128], uu[128], v[1152], red[4];
    const float* W; int O, K;
    switch (blockIdx.x) {
        case 0:  W = cW1; O = 128; K = 576;  break;
        case 1:  W = cW2; O = 64;  K = 1152; break;
        case 2:  W = fW1; O = 128; K = 1152; break;
        default: W = fW2; O = 64;  K = 1152; break;
    }
    int tid = threadIdx.x;
    if (tid < O) u[tid] = 1.0f / sqrtf((float)O);
    __syncthreads();
    for (int it = 0; it < 3; ++it) {
        // v = Wm^T u
        for (int k = tid; k < K; k += 256) {
            float s = 0.f;
            for (int o = 0; o < O; ++o) s += W[(size_t)o * K + k] * u[o];
            v[k] = s;
        }
        __syncthreads();
        float loc = 0.f;
        for (int k = tid; k < K; k += 256) loc += v[k] * v[k];
        float nv = sqrtf(block_sum(loc, red));
        for (int k = tid; k < K; k += 256) v[k] = v[k] / (nv + 1e-12f);
        __syncthreads();
        // uu = Wm v
        if (tid < O) {
            float s = 0.f;
            for (int k = 0; k < K; ++k) s += W[(size_t)tid * K + k] * v[k];
            uu[tid] = s;
        }
        __syncthreads();
        loc = (tid < O) ? uu[tid] * uu[tid] : 0.f;
        float nu = sqrtf(block_sum(loc, red));
        if (tid < O) u[tid] = uu[tid] / (nu + 1e-12f);
        __syncthreads();
    }
    float loc = (tid < O) ? u[tid] * uu[tid] : 0.f;
    float sg = block_sum(loc, red);
    if (tid == 0) sig[blockIdx.x] = sg;
}

// ---------------- weight prep: transpose (+ 1/sigma for convs) ----------------
__global__ __launch_bounds__(256)
void prep_weights(const float* s0, const float* s1, const float* s2, const float* s3,
                  const float* s4, const float* s5, const float* s6, const float* s7,
                  const float* s8, const float* s9, const float* s10, const float* s11,
                  const float* __restrict__ sigma, float* __restrict__ ws) {
    const float* srcs[12] = {s0,s1,s2,s3,s4,s5,s6,s7,s8,s9,s10,s11};
    const int    Os[12]   = {128,64,128,64, 128,128,128,128, 64,64,64,64};
    const int    Ks[12]   = {576,1152,1152,1152, 64,64,64,64, 128,128,128,128};
    const int    sg[12]   = {0,1,2,3, -1,-1,-1,-1, -1,-1,-1,-1};
    const size_t dof[12]  = {WT_C1,WT_C2,WT_F1,WT_F2, WT_Q1,WT_K1,WT_V1,WT_S1,
                             WT_Q2,WT_K2,WT_V2,WT_S2};
    int w = blockIdx.y;
    int e = blockIdx.x * 256 + threadIdx.x;
    int O = Os[w], K = Ks[w];
    if (e >= O * K) return;
    int o = e / K, k = e - o * K;
    float v = srcs[w][e];
    if (sg[w] >= 0) v = v / sigma[sg[w]];
    ws[dof[w] + (size_t)k * O + o] = v;
}

// ---------------- generic fp32 GEMM: C[MxN] = gather(A)[MxK] * B[KxN] + bias ----------------
// MODE 0: A0 dense row-major [M x K]
// MODE 1: A0 NCHW (B, K, 64, 64)  (1x1 "conv" gather)
// MODE 2: A0 NCHW (B, cin, 64, 64), im2col 3x3 edge-clamped, K = cin*9
// MODE 3: concat: ci<64 from A0 (NCHW 64ch); ci>=64 from A1 [(N) x 64 row-major]
template<int MODE>
__global__ __launch_bounds__(256)
void gemm_kernel(const float* __restrict__ A0, const float* __restrict__ A1,
                 const float* __restrict__ B, const float* __restrict__ bias,
                 float* __restrict__ C, int M, int N, int K, int cin,
                 int out_nchw, int do_gelu) {
    __shared__ float As[16][64];
    __shared__ float Bs[16][64];
    const int tid = threadIdx.x;
    const int mtile = blockIdx.x, ntile = blockIdx.y;
    const int m0 = mtile * 64;
    const int tm = tid >> 4, tn = tid & 15;
    const int bimg = m0 >> 12;
    const int yrow = (m0 >> 6) & 63;

    float acc[4][4] = {};
    const int nsteps = K >> 4;
    for (int kt = 0; kt < nsteps; ++kt) {
        #pragma unroll
        for (int i = 0; i < 4; ++i) {
            int idx = tid + i * 256;
            int kl = idx >> 6, ml = idx & 63;
            int kg = kt * 16 + kl;
            float val;
            if (MODE == 0) {
                val = A0[(size_t)(m0 + ml) * K + kg];
            } else if (MODE == 1) {
                val = A0[((size_t)(bimg * K + kg) << 12) + yrow * 64 + ml];
            } else {
                int ci = kg / 9, tap = kg - ci * 9;
                int dy = tap / 3 - 1, dx = tap - (tap / 3) * 3 - 1;
                int yy = yrow + dy; yy = yy < 0 ? 0 : (yy > 63 ? 63 : yy);
                int xx = ml + dx;   xx = xx < 0 ? 0 : (xx > 63 ? 63 : xx);
                if (MODE == 2 || ci < 64) {
                    int CC = (MODE == 3) ? 64 : cin;
                    val = A0[((size_t)(bimg * CC + ci) << 12) + (yy << 6) + xx];
                } else {
                    val = A1[(((size_t)(bimg << 12) + (yy << 6) + xx) << 6) + (ci - 64)];
                }
            }
            As[kl][ml] = val;
        }
        #pragma unroll
        for (int i = 0; i < 4; ++i) {
            int idx = tid + i * 256;
            int kl = idx >> 6, nl = idx & 63;
            Bs[kl][nl] = B[(size_t)(kt * 16 + kl) * N + ntile * 64 + nl];
        }
        __syncthreads();
        #pragma unroll
        for (int k = 0; k < 16; ++k) {
            float av[4], bv[4];
            *reinterpret_cast<float4*>(av) = *reinterpret_cast<const float4*>(&As[k][tm * 4]);
            *reinterpret_cast<float4*>(bv) = *reinterpret_cast<const float4*>(&Bs[k][tn * 4]);
            #pragma unroll
            for (int i = 0; i < 4; ++i)
                #pragma unroll
                for (int j = 0; j < 4; ++j)
                    acc[i][j] += av[i] * bv[j];
        }
        __syncthreads();
    }
    // epilogue
    if (out_nchw) {
        int sp = (m0 & 4095) + tm * 4;
        #pragma unroll
        for (int j = 0; j < 4; ++j) {
            int o = ntile * 64 + tn * 4 + j;
            float bj = bias[o];
            float st[4];
            #pragma unroll
            for (int i = 0; i < 4; ++i) {
                float vv = acc[i][j] + bj;
                st[i] = do_gelu ? gelu_f(vv) : vv;
            }
            *reinterpret_cast<float4*>(&C[((size_t)(bimg * N + o) << 12) + sp]) =
                *reinterpret_cast<float4*>(st);
        }
    } else {
        #pragma unroll
        for (int i = 0; i < 4; ++i) {
            int m = m0 + tm * 4 + i;
            float st[4];
            #pragma unroll
            for (int j = 0; j < 4; ++j) {
                float vv = acc[i][j] + bias[ntile * 64 + tn * 4 + j];
                st[j] = do_gelu ? gelu_f(vv) : vv;
            }
            *reinterpret_cast<float4*>(&C[(size_t)m * N + ntile * 64 + tn * 4]) =
                *reinterpret_cast<float4*>(st);
        }
    }
}

// ---------------- attention layer 1: heads=8, d=16, 3x3 stencil ----------------
// H holds the s-term on entry; overwritten with gelu(attn + s-term).
__global__ __launch_bounds__(256)
void attn1_kernel(const float* __restrict__ Q, const float* __restrict__ K,
                  const float* __restrict__ V, float* __restrict__ H) {
    int wid = threadIdx.x >> 6, lane = threadIdx.x & 63;
    int n = (blockIdx.x << 2) + wid;
    int y = (n >> 6) & 63, x = n & 63;
    size_t base = (size_t)n * 128;
    float q0 = Q[base + lane], q1 = Q[base + 64 + lane];
    float a0[9], a1[9];
    float m0 = -1e30f, m1 = -1e30f;
    #pragma unroll
    for (int e = 0; e < 9; ++e) {
        int dy = e / 3 - 1, dx = e % 3 - 1;
        int yy = y + dy, xx = x + dx;
        if ((unsigned)yy < 64u && (unsigned)xx < 64u) {
            size_t kb = (size_t)(n + dy * 64 + dx) * 128;
            float p0 = q0 * K[kb + lane];
            float p1 = q1 * K[kb + 64 + lane];
            #pragma unroll
            for (int msk = 1; msk < 16; msk <<= 1) {
                p0 += __shfl_xor(p0, msk);
                p1 += __shfl_xor(p1, msk);
            }
            p0 *= 0.25f; p1 *= 0.25f;   // 1/sqrt(16)
            a0[e] = p0; a1[e] = p1;
            m0 = fmaxf(m0, p0); m1 = fmaxf(m1, p1);
        } else { a0[e] = -1e30f; a1[e] = -1e30f; }
    }
    float s0 = 0.f, s1 = 0.f;
    #pragma unroll
    for (int e = 0; e < 9; ++e) {
        a0[e] = expf(a0[e] - m0); s0 += a0[e];
        a1[e] = expf(a1[e] - m1); s1 += a1[e];
    }
    float r0 = 1.f / (s0 + 1e-16f), r1 = 1.f / (s1 + 1e-16f);
    #pragma unroll
    for (int e = 0; e < 9; ++e) { a0[e] *= r0; a1[e] *= r1; }
    float o0 = 0.f, o1 = 0.f;
    #pragma unroll
    for (int e = 0; e < 9; ++e) {
        int dy = e / 3 - 1, dx = e % 3 - 1;
        int yy = y + dy, xx = x + dx;
        if ((unsigned)yy < 64u && (unsigned)xx < 64u) {
            size_t kb = (size_t)(n + dy * 64 + dx) * 128;
            o0 += a0[e] * V[kb + lane];
            o1 += a1[e] * V[kb + 64 + lane];
        }
    }
    H[base + lane]      = gelu_f(o0 + H[base + lane]);
    H[base + 64 + lane] = gelu_f(o1 + H[base + 64 + lane]);
}

// ---------------- attention layer 2: heads=1, d=64 ----------------
__global__ __launch_bounds__(256)
void attn2_kernel(const float* __restrict__ Q, const float* __restrict__ K,
                  const float* __restrict__ V, float* __restrict__ H) {
    int wid = threadIdx.x >> 6, lane = threadIdx.x & 63;
    int n = (blockIdx.x << 2) + wid;
    int y = (n >> 6) & 63, x = n & 63;
    size_t base = (size_t)n * 64;
    float q = Q[base + lane];
    float a[9]; float mx = -1e30f;
    #pragma unroll
    for (int e = 0; e < 9; ++e) {
        int dy = e / 3 - 1, dx = e % 3 - 1;
        int yy = y + dy, xx = x + dx;
        if ((unsigned)yy < 64u && (unsigned)xx < 64u) {
            size_t kb = (size_t)(n + dy * 64 + dx) * 64;
            float p = q * K[kb + lane];
            #pragma unroll
            for (int msk = 1; msk < 64; msk <<= 1) p += __shfl_xor(p, msk);
            p *= 0.125f;  // 1/sqrt(64)
            a[e] = p; mx = fmaxf(mx, p);
        } else a[e] = -1e30f;
    }
    float s = 0.f;
    #pragma unroll
    for (int e = 0; e < 9; ++e) { a[e] = expf(a[e] - mx); s += a[e]; }
    float r = 1.f / (s + 1e-16f);
    float o = 0.f;
    #pragma unroll
    for (int e = 0; e < 9; ++e) {
        int dy = e / 3 - 1, dx = e % 3 - 1;
        int yy = y + dy, xx = x + dx;
        if ((unsigned)yy < 64u && (unsigned)xx < 64u) {
            size_t kb = (size_t)(n + dy * 64 + dx) * 64;
            o += a[e] * V[kb + lane];
        }
    }
    o *= r;
    H[base + lane] = gelu_f(o + H[base + lane]);
}

// ---------------- host launcher ----------------
extern "C" void kernel_launch(void* const* d_in, const int* in_sizes, int n_in,
                              void* d_out, int out_size, void* d_ws, size_t ws_size,
                              hipStream_t stream) {
    const float* x   = (const float*)d_in[0];
    const float* cW1 = (const float*)d_in[1];
    const float* cb1 = (const float*)d_in[2];
    const float* cW2 = (const float*)d_in[3];
    const float* cb2 = (const float*)d_in[4];
    const float* q1W = (const float*)d_in[5];
    const float* q1b = (const float*)d_in[6];
    const float* k1W = (const float*)d_in[7];
    const float* k1b = (const float*)d_in[8];
    const float* v1W = (const float*)d_in[9];
    const float* v1b = (const float*)d_in[10];
    const float* s1W = (const float*)d_in[11];
    const float* s1b = (const float*)d_in[12];
    const float* q2W = (const float*)d_in[13];
    const float* q2b = (const float*)d_in[14];
    const float* k2W = (const float*)d_in[15];
    const float* k2b = (const float*)d_in[16];
    const float* v2W = (const float*)d_in[17];
    const float* v2b = (const float*)d_in[18];
    const float* s2W = (const float*)d_in[19];
    const float* s2b = (const float*)d_in[20];
    const float* fW1 = (const float*)d_in[21];
    const float* fb1 = (const float*)d_in[22];
    const float* fW2 = (const float*)d_in[23];
    const float* fb2 = (const float*)d_in[24];
    float* ws  = (float*)d_ws;
    float* out = (float*)d_out;

    // 1. spectral norms
    sigma_kernel<<<4, 256, 0, stream>>>(cW1, cW2, fW1, fW2, ws + SIGMA_OFF);

    // 2. weight transpose / scale
    prep_weights<<<dim3(576, 12), 256, 0, stream>>>(
        cW1, cW2, fW1, fW2, q1W, k1W, v1W, s1W, q2W, k2W, v2W, s2W,
        ws + SIGMA_OFF, ws);

    dim3 g1(1024, 1), g2(1024, 2);
    // 3. layer-1 projections (A = x in NCHW, K=64)
    gemm_kernel<1><<<g2, 256, 0, stream>>>(x, nullptr, ws + WT_Q1, q1b, ws + BUFA,
                                           NPIX, 128, 64, 64, 0, 0);
    gemm_kernel<1><<<g2, 256, 0, stream>>>(x, nullptr, ws + WT_K1, k1b, ws + BUFB,
                                           NPIX, 128, 64, 64, 0, 0);
    gemm_kernel<1><<<g2, 256, 0, stream>>>(x, nullptr, ws + WT_V1, v1b, ws + BUFC,
                                           NPIX, 128, 64, 64, 0, 0);
    gemm_kernel<1><<<g2, 256, 0, stream>>>(x, nullptr, ws + WT_S1, s1b, ws + BUFD,
                                           NPIX, 128, 64, 64, 0, 0);
    // 4. attention 1  (writes h into BUFD)
    attn1_kernel<<<NPIX / 4, 256, 0, stream>>>(ws + BUFA, ws + BUFB, ws + BUFC, ws + BUFD);

    // 5. layer-2 projections (A = h dense, K=128)
    gemm_kernel<0><<<g1, 256, 0, stream>>>(ws + BUFD, nullptr, ws + WT_Q2, q2b, ws + BUFC,
                                           NPIX, 64, 128, 0, 0, 0);
    gemm_kernel<0><<<g1, 256, 0, stream>>>(ws + BUFD, nullptr, ws + WT_K2, k2b, ws + BUFC2,
                                           NPIX, 64, 128, 0, 0, 0);
    gemm_kernel<0><<<g1, 256, 0, stream>>>(ws + BUFD, nullptr, ws + WT_V2, v2b, ws + BUFE,
                                           NPIX, 64, 128, 0, 0, 0);
    gemm_kernel<0><<<g1, 256, 0, stream>>>(ws + BUFD, nullptr, ws + WT_S2, s2b, ws + BUFF,
                                           NPIX, 64, 128, 0, 0, 0);
    // 6. attention 2  (writes x2 into BUFF)
    attn2_kernel<<<NPIX / 4, 256, 0, stream>>>(ws + BUFC, ws + BUFC2, ws + BUFE, ws + BUFF);

    // 7. conv1: x -> y1 (BUFA, 128ch NCHW)
    gemm_kernel<2><<<g2, 256, 0, stream>>>(x, nullptr, ws + WT_C1, cb1, ws + BUFA,
                                           NPIX, 128, 576, 64, 1, 1);
    // 8. conv2: y1 -> x1 (BUFE, 64ch NCHW)
    gemm_kernel<2><<<g1, 256, 0, stream>>>(ws + BUFA, nullptr, ws + WT_C2, cb2, ws + BUFE,
                                           NPIX, 64, 1152, 128, 1, 1);
    // 9. conv3: concat(x1, x2) -> t (BUFB, 128ch NCHW)
    gemm_kernel<3><<<g2, 256, 0, stream>>>(ws + BUFE, ws + BUFF, ws + WT_F1, fb1, ws + BUFB,
                                           NPIX, 128, 1152, 64, 1, 1);
    // 10. conv4: t -> out (64ch NCHW)
    gemm_kernel<2><<<g1, 256, 0, stream>>>(ws + BUFB, nullptr, ws + WT_F2, fb2, out,
                                           NPIX, 64, 1152, 128, 1, 1);
}

// Round 2
// 528.916 us; speedup vs baseline: 2.9194x; 2.9194x over previous
//
#include <hip/hip_runtime.h>
#include <hip/hip_bf16.h>

typedef unsigned int  u32;
typedef unsigned short u16;
typedef __attribute__((ext_vector_type(8))) short bf16x8;
typedef __attribute__((ext_vector_type(4))) float f32x4;

#define NPIX 65536

// ---------------- ws byte offsets ----------------
constexpr size_t SIG   = 0;                   // 4 floats
constexpr size_t B1OFF = 256;                 // 512 f32
constexpr size_t B2OFF = B1OFF + 2048;        // 256 f32
constexpr size_t WC1   = B2OFF + 1024;        // 128x576 bf16
constexpr size_t WC2   = WC1 + 147456;        // 64x1152
constexpr size_t WF1   = WC2 + 147456;        // 128x1152
constexpr size_t WF2   = WF1 + 294912;        // 64x1152
constexpr size_t WP1   = WF2 + 147456;        // 512x64
constexpr size_t WP2   = WP1 + 65536;         // 256x128
constexpr size_t XB    = WP2 + 65536;         // 65536x64 bf16 (8 MB)
constexpr size_t HBUF  = XB + 8388608;        // 65536x128 bf16 (16 MB)
constexpr size_t QKVS2 = HBUF + 16777216;     // 65536x256 bf16 (32 MB)
constexpr size_t XC    = QKVS2 + 33554432;    // 65536x128 bf16 (16 MB) concat buf
constexpr size_t QKVS1 = XC + 16777216;       // 65536x512 bf16 (64 MB)
constexpr size_t Y1    = QKVS1;               // alias: y1 lives after qkvs1 dead
constexpr size_t TBUF  = QKVS1 + 16777216;    // alias: t
// total = QKVS1 + 64MB = ~137 MB

// ---------------- helpers ----------------
__device__ __forceinline__ float gelu_f(float v) {
    return 0.5f * v * (1.0f + erff(v * 0.70710678118654752f));
}
__device__ __forceinline__ u16 f2bf(float f) {
    __hip_bfloat16 b = __float2bfloat16(f);
    return *reinterpret_cast<u16*>(&b);
}
__device__ __forceinline__ float blo(u32 u) {
    union { u32 i; float f; } x; x.i = u << 16; return x.f;
}
__device__ __forceinline__ float bhi(u32 u) {
    union { u32 i; float f; } x; x.i = u & 0xffff0000u; return x.f;
}
__device__ __forceinline__ void g2l16(const void* g, void* l) {
    __builtin_amdgcn_global_load_lds(
        (const __attribute__((address_space(1))) u32*)g,
        (__attribute__((address_space(3))) u32*)l, 16, 0, 0);
}

// ---------------- block reduction ----------------
__device__ float block_sum(float vv, float* red) {
    #pragma unroll
    for (int m = 1; m < 64; m <<= 1) vv += __shfl_xor(vv, m);
    int tid = threadIdx.x;
    __syncthreads();
    if ((tid & 63) == 0) red[tid >> 6] = vv;
    __syncthreads();
    return red[0] + red[1] + red[2] + red[3];
}

// ---------------- spectral norm sigma ----------------
__global__ __launch_bounds__(256)
void sigma_kernel(const float* __restrict__ cW1, const float* __restrict__ cW2,
                  const float* __restrict__ fW1, const float* __restrict__ fW2,
                  float* __restrict__ sig) {
    __shared__ float u[128], uu[128], vsh[1152], red[4], pp[256];
    const float* W; int O, K;
    switch (blockIdx.x) {
        case 0:  W = cW1; O = 128; K = 576;  break;
        case 1:  W = cW2; O = 64;  K = 1152; break;
        case 2:  W = fW1; O = 128; K = 1152; break;
        default: W = fW2; O = 64;  K = 1152; break;
    }
    int tid = threadIdx.x;
    // warm L2 with coalesced streaming read of W
    {
        float dummy = 0.f;
        int total = O * K;
        for (int i = tid * 4; i < total; i += 1024) {
            float4 t = *reinterpret_cast<const float4*>(&W[i]);
            dummy += t.x + t.y + t.z + t.w;
        }
        asm volatile("" :: "v"(dummy));
    }
    if (tid < O) u[tid] = 1.0f / sqrtf((float)O);
    __syncthreads();
    const int per = 256 / O;          // threads per output row (2 or 4)
    const int kc  = K / per;
    const int o_ = tid % O, part = tid / O;
    for (int it = 0; it < 3; ++it) {
        // v = Wm^T u
        for (int k = tid; k < K; k += 256) {
            float s = 0.f;
            for (int o = 0; o < O; ++o) s += W[(size_t)o * K + k] * u[o];
            vsh[k] = s;
        }
        __syncthreads();
        float loc = 0.f;
        for (int k = tid; k < K; k += 256) loc += vsh[k] * vsh[k];
        float nv = sqrtf(block_sum(loc, red));
        for (int k = tid; k < K; k += 256) vsh[k] = vsh[k] / (nv + 1e-12f);
        __syncthreads();
        // uu = Wm v  (parallel over all 256 threads)
        {
            float s = 0.f;
            const float* wr = W + (size_t)o_ * K + part * kc;
            for (int k = 0; k < kc; ++k) s += wr[k] * vsh[part * kc + k];
            pp[tid] = s;
        }
        __syncthreads();
        if (tid < O) {
            float s = 0.f;
            for (int j = 0; j < per; ++j) s += pp[tid + j * O];
            uu[tid] = s;
        }
        __syncthreads();
        float loc2 = (tid < O) ? uu[tid] * uu[tid] : 0.f;
        float nu = sqrtf(block_sum(loc2, red));
        if (tid < O) u[tid] = uu[tid] / (nu + 1e-12f);
        __syncthreads();
    }
    float loc = (tid < O) ? u[tid] * uu[tid] : 0.f;
    float sg = block_sum(loc, red);
    if (tid == 0) sig[blockIdx.x] = sg;
}

// ---------------- conv weight prep: [O][C][3][3]/sigma -> bf16 [O][tap*C+ci] ----------------
__global__ __launch_bounds__(256)
void prep_conv_w(const float* __restrict__ cW1, const float* __restrict__ cW2,
                 const float* __restrict__ fW1, const float* __restrict__ fW2,
                 const float* __restrict__ sig,
                 u16* wc1, u16* wc2, u16* wf1, u16* wf2) {
    int wsel = blockIdx.y;
    const float* src; u16* dst; int O, C;
    switch (wsel) {
        case 0:  src = cW1; dst = wc1; O = 128; C = 64;  break;
        case 1:  src = cW2; dst = wc2; O = 64;  C = 128; break;
        case 2:  src = fW1; dst = wf1; O = 128; C = 128; break;
        default: src = fW2; dst = wf2; O = 64;  C = 128; break;
    }
    int idx = blockIdx.x * 256 + threadIdx.x;
    if (idx >= O * C * 9) return;
    int o = idx / (C * 9);
    int rem = idx - o * (C * 9);
    int ci = rem / 9, tap = rem - ci * 9;
    float v = src[idx] / sig[wsel];
    dst[(size_t)o * (C * 9) + tap * C + ci] = f2bf(v);
}

// ---------------- projection weight/bias prep (fused QKVS) ----------------
__global__ __launch_bounds__(256)
void prep_proj(const float* q1W, const float* k1W, const float* v1W, const float* s1W,
               const float* q2W, const float* k2W, const float* v2W, const float* s2W,
               const float* q1b, const float* k1b, const float* v1b, const float* s1b,
               const float* q2b, const float* k2b, const float* v2b, const float* s2b,
               u16* wp1, u16* wp2, float* b1, float* b2) {
    const float* W1[4] = {q1W, k1W, v1W, s1W};
    const float* W2[4] = {q2W, k2W, v2W, s2W};
    const float* Bb1[4] = {q1b, k1b, v1b, s1b};
    const float* Bb2[4] = {q2b, k2b, v2b, s2b};
    int idx = blockIdx.x * 256 + threadIdx.x;
    if (idx < 32768) {
        int w = idx >> 13, r = idx & 8191;       // [128][64] contiguous
        wp1[(size_t)w * 8192 + r] = f2bf(W1[w][r]);
    } else if (idx < 65536) {
        int j = idx - 32768; int w = j >> 13, r = j & 8191;  // [64][128]
        wp2[(size_t)w * 8192 + r] = f2bf(W2[w][r]);
    } else if (idx < 66048) {
        int j = idx - 65536; int w = j >> 7; b1[j] = Bb1[w][j & 127];
    } else if (idx < 66304) {
        int j = idx - 66048; int w = j >> 6; b2[j] = Bb2[w][j & 63];
    }
}

// ---------------- x NCHW f32 -> [pix][64] bf16 ----------------
__global__ __launch_bounds__(256)
void convert_x(const float* __restrict__ x, u16* __restrict__ xb) {
    __shared__ float tile[64][65];
    int b = blockIdx.x >> 6, y = blockIdx.x & 63;
    int tid = threadIdx.x;
    #pragma unroll
    for (int i = 0; i < 16; ++i) {
        int c = (tid >> 6) + i * 4;
        tile[c][tid & 63] = x[(((size_t)b * 64 + c) << 12) + (y << 6) + (tid & 63)];
    }
    __syncthreads();
    #pragma unroll
    for (int i = 0; i < 16; ++i) {
        int idx = tid + i * 256;
        int p = idx >> 6, c = idx & 63;
        xb[(((size_t)b << 12) + (y << 6) + p) * 64 + c] = f2bf(tile[c][p]);
    }
}

// ---------------- bf16 MFMA GEMM, implicit im2col (edge-clamped 3x3) ----------------
// A: [NPIX][CC] bf16 activations. Bw: [N][K] bf16 (K = CC*TAPS, tap-major).
// OUTM 0: bf16 out at Cout[m*ostride + ocol0 + n]; OUTM 1: f32 NCHW out.
template<int TAPS, int CC, int BN, int OUTM>
__global__ __launch_bounds__(256)
void mm_kernel(const u16* __restrict__ A, const u16* __restrict__ Bw,
               const float* __restrict__ bias, void* __restrict__ Cout,
               int ostride, int ocol0, int do_gelu) {
    constexpr int K = CC * TAPS;
    constexpr int NSTEP = K / 32;
    constexpr int NF = BN / 32;
    constexpr int HN = BN / 2;
    __shared__ u16 Als[128 * 32];
    __shared__ u16 Bls[BN * 32];
    const int tid = threadIdx.x;
    const int w = tid >> 6;
    const int lane = tid & 63;
    const int m0 = blockIdx.x * 128;
    const int nt0 = blockIdx.y * BN;
    const int wm = w >> 1, wn = w & 1;

    f32x4 acc[4][NF];
    #pragma unroll
    for (int i = 0; i < 4; ++i)
        #pragma unroll
        for (int j = 0; j < NF; ++j) {
            f32x4 z = {0.f, 0.f, 0.f, 0.f};
            acc[i][j] = z;
        }

    #pragma unroll 2
    for (int kt = 0; kt < NSTEP; ++kt) {
        const int kk = kt * 32;
        int tap = 0, ci0 = kk;
        if (TAPS == 9) { tap = kk / CC; ci0 = kk - tap * CC; }
        const int dy = tap / 3 - 1, dx2 = tap % 3 - 1;
        // stage A tile [128][32]
        #pragma unroll
        for (int r = 0; r < 2; ++r) {
            int row = (tid >> 2) + r * 64;
            int m = m0 + row;
            int q;
            if (TAPS == 9) {
                int yy = ((m >> 6) & 63) + dy; yy = yy < 0 ? 0 : (yy > 63 ? 63 : yy);
                int xx = (m & 63) + dx2;       xx = xx < 0 ? 0 : (xx > 63 ? 63 : xx);
                q = (m & ~4095) | (yy << 6) | xx;
            } else q = m;
            const u16* g = A + (size_t)q * CC + ci0 + (tid & 3) * 8;
            g2l16(g, &Als[w * 512 + r * 2048]);
        }
        // stage B tile [BN][32]  (Bw rows are K-contiguous)
        #pragma unroll
        for (int r = 0; r < BN / 64; ++r) {
            int row = (tid >> 2) + r * 64;
            const u16* g = Bw + (size_t)(nt0 + row) * K + kk + (tid & 3) * 8;
            g2l16(g, &Bls[w * 512 + r * 2048]);
        }
        __syncthreads();
        bf16x8 af[4];
        #pragma unroll
        for (int mf = 0; mf < 4; ++mf)
            af[mf] = *reinterpret_cast<const bf16x8*>(
                &Als[(wm * 64 + mf * 16 + (lane & 15)) * 32 + (lane >> 4) * 8]);
        #pragma unroll
        for (int nf = 0; nf < NF; ++nf) {
            bf16x8 bfv = *reinterpret_cast<const bf16x8*>(
                &Bls[(wn * HN + nf * 16 + (lane & 15)) * 32 + (lane >> 4) * 8]);
            #pragma unroll
            for (int mf = 0; mf < 4; ++mf)
                acc[mf][nf] = __builtin_amdgcn_mfma_f32_16x16x32_bf16(
                    af[mf], bfv, acc[mf][nf], 0, 0, 0);
        }
        __syncthreads();
    }

    // epilogue
    #pragma unroll
    for (int mf = 0; mf < 4; ++mf) {
        int mrow = m0 + wm * 64 + mf * 16 + (lane >> 4) * 4;
        #pragma unroll
        for (int nf = 0; nf < NF; ++nf) {
            int col = nt0 + wn * HN + nf * 16 + (lane & 15);
            float bv = bias[col];
            if (OUTM == 0) {
                u16* Co = (u16*)Cout;
                #pragma unroll
                for (int j = 0; j < 4; ++j) {
                    float v = acc[mf][nf][j] + bv;
                    if (do_gelu) v = gelu_f(v);
                    Co[(size_t)(mrow + j) * ostride + ocol0 + col] = f2bf(v);
                }
            } else {
                float* Co = (float*)Cout;
                int b = m0 >> 12;
                int pixb = (mrow & 4095);
                f32x4 vv;
                #pragma unroll
                for (int j = 0; j < 4; ++j) {
                    float v = acc[mf][nf][j] + bv;
                    vv[j] = gelu_f(v);
                }
                *reinterpret_cast<f32x4*>(&Co[((size_t)(b * 64 + col)) * 4096 + pixb]) = vv;
            }
        }
    }
}

// ---------------- attention layer 1: heads=8, d=16 ----------------
__global__ __launch_bounds__(256)
void attn1_kernel(const u16* __restrict__ qkvs, u16* __restrict__ h) {
    int wid = threadIdx.x >> 6, lane = threadIdx.x & 63;
    int n = blockIdx.x * 4 + wid;
    int y = (n >> 6) & 63, x = n & 63;
    u32 qp = ((const u32*)(qkvs + (size_t)n * 512))[lane];
    float q0 = blo(qp), q1 = bhi(qp);
    float al[9], mx = -1e30f;
    #pragma unroll
    for (int e = 0; e < 9; ++e) {
        int dy = e / 3 - 1, dx = e % 3 - 1;
        if ((unsigned)(y + dy) < 64u && (unsigned)(x + dx) < 64u) {
            u32 kp = ((const u32*)(qkvs + (size_t)(n + dy * 64 + dx) * 512 + 128))[lane];
            float p = q0 * blo(kp) + q1 * bhi(kp);
            p += __shfl_xor(p, 1); p += __shfl_xor(p, 2); p += __shfl_xor(p, 4);
            al[e] = p * 0.25f;
            mx = fmaxf(mx, al[e]);
        } else al[e] = -1e30f;
    }
    float s = 0.f;
    #pragma unroll
    for (int e = 0; e < 9; ++e) { al[e] = expf(al[e] - mx); s += al[e]; }
    float o0 = 0.f, o1 = 0.f;
    #pragma unroll
    for (int e = 0; e < 9; ++e) {
        int dy = e / 3 - 1, dx = e % 3 - 1;
        if ((unsigned)(y + dy) < 64u && (unsigned)(x + dx) < 64u) {
            u32 vp = ((const u32*)(qkvs + (size_t)(n + dy * 64 + dx) * 512 + 256))[lane];
            o0 += al[e] * blo(vp); o1 += al[e] * bhi(vp);
        }
    }
    float r = 1.f / (s + 1e-16f);
    u32 sp = ((const u32*)(qkvs + (size_t)n * 512 + 384))[lane];
    float h0 = gelu_f(o0 * r + blo(sp));
    float h1 = gelu_f(o1 * r + bhi(sp));
    ((u32*)(h + (size_t)n * 128))[lane] = (u32)f2bf(h0) | ((u32)f2bf(h1) << 16);
}

// ---------------- attention layer 2: heads=1, d=64 -> xc cols 64..127 ----------------
__global__ __launch_bounds__(256)
void attn2_kernel(const u16* __restrict__ qkvs, u16* __restrict__ xc) {
    int sub = threadIdx.x >> 5, hl = threadIdx.x & 31;
    int n = blockIdx.x * 8 + sub;
    int y = (n >> 6) & 63, x = n & 63;
    u32 qp = ((const u32*)(qkvs + (size_t)n * 256))[hl];
    float q0 = blo(qp), q1 = bhi(qp);
    float al[9], mx = -1e30f;
    #pragma unroll
    for (int e = 0; e < 9; ++e) {
        int dy = e / 3 - 1, dx = e % 3 - 1;
        if ((unsigned)(y + dy) < 64u && (unsigned)(x + dx) < 64u) {
            u32 kp = ((const u32*)(qkvs + (size_t)(n + dy * 64 + dx) * 256 + 64))[hl];
            float p = q0 * blo(kp) + q1 * bhi(kp);
            p += __shfl_xor(p, 1); p += __shfl_xor(p, 2); p += __shfl_xor(p, 4);
            p += __shfl_xor(p, 8); p += __shfl_xor(p, 16);
            al[e] = p * 0.125f;
            mx = fmaxf(mx, al[e]);
        } else al[e] = -1e30f;
    }
    float s = 0.f;
    #pragma unroll
    for (int e = 0; e < 9; ++e) { al[e] = expf(al[e] - mx); s += al[e]; }
    float o0 = 0.f, o1 = 0.f;
    #pragma unroll
    for (int e = 0; e < 9; ++e) {
        int dy = e / 3 - 1, dx = e % 3 - 1;
        if ((unsigned)(y + dy) < 64u && (unsigned)(x + dx) < 64u) {
            u32 vp = ((const u32*)(qkvs + (size_t)(n + dy * 64 + dx) * 256 + 128))[hl];
            o0 += al[e] * blo(vp); o1 += al[e] * bhi(vp);
        }
    }
    float r = 1.f / (s + 1e-16f);
    u32 sp = ((const u32*)(qkvs + (size_t)n * 256 + 192))[hl];
    float h0 = gelu_f(o0 * r + blo(sp));
    float h1 = gelu_f(o1 * r + bhi(sp));
    ((u32*)(xc + (size_t)n * 128 + 64))[hl] = (u32)f2bf(h0) | ((u32)f2bf(h1) << 16);
}

// ---------------- host launcher ----------------
extern "C" void kernel_launch(void* const* d_in, const int* in_sizes, int n_in,
                              void* d_out, int out_size, void* d_ws, size_t ws_size,
                              hipStream_t stream) {
    const float* x   = (const float*)d_in[0];
    const float* cW1 = (const float*)d_in[1];
    const float* cb1 = (const float*)d_in[2];
    const float* cW2 = (const float*)d_in[3];
    const float* cb2 = (const float*)d_in[4];
    const float* q1W = (const float*)d_in[5];
    const float* q1b = (const float*)d_in[6];
    const float* k1W = (const float*)d_in[7];
    const float* k1b = (const float*)d_in[8];
    const float* v1W = (const float*)d_in[9];
    const float* v1b = (const float*)d_in[10];
    const float* s1W = (const float*)d_in[11];
    const float* s1b = (const float*)d_in[12];
    const float* q2W = (const float*)d_in[13];
    const float* q2b = (const float*)d_in[14];
    const float* k2W = (const float*)d_in[15];
    const float* k2b = (const float*)d_in[16];
    const float* v2W = (const float*)d_in[17];
    const float* v2b = (const float*)d_in[18];
    const float* s2W = (const float*)d_in[19];
    const float* s2b = (const float*)d_in[20];
    const float* fW1 = (const float*)d_in[21];
    const float* fb1 = (const float*)d_in[22];
    const float* fW2 = (const float*)d_in[23];
    const float* fb2 = (const float*)d_in[24];

    char* ws = (char*)d_ws;
    float* sig  = (float*)(ws + SIG);
    float* b1   = (float*)(ws + B1OFF);
    float* b2   = (float*)(ws + B2OFF);
    u16* wc1    = (u16*)(ws + WC1);
    u16* wc2    = (u16*)(ws + WC2);
    u16* wf1    = (u16*)(ws + WF1);
    u16* wf2    = (u16*)(ws + WF2);
    u16* wp1    = (u16*)(ws + WP1);
    u16* wp2    = (u16*)(ws + WP2);
    u16* xb     = (u16*)(ws + XB);
    u16* hbuf   = (u16*)(ws + HBUF);
    u16* qkvs2  = (u16*)(ws + QKVS2);
    u16* xc     = (u16*)(ws + XC);
    u16* qkvs1  = (u16*)(ws + QKVS1);
    u16* y1     = (u16*)(ws + Y1);
    u16* tbuf   = (u16*)(ws + TBUF);
    float* out  = (float*)d_out;

    sigma_kernel<<<4, 256, 0, stream>>>(cW1, cW2, fW1, fW2, sig);
    prep_conv_w<<<dim3(576, 4), 256, 0, stream>>>(cW1, cW2, fW1, fW2, sig,
                                                  wc1, wc2, wf1, wf2);
    prep_proj<<<260, 256, 0, stream>>>(q1W, k1W, v1W, s1W, q2W, k2W, v2W, s2W,
                                       q1b, k1b, v1b, s1b, q2b, k2b, v2b, s2b,
                                       wp1, wp2, b1, b2);
    convert_x<<<1024, 256, 0, stream>>>(x, xb);

    // proj1: [N][64] x [512][64]^T -> qkvs1 [N][512]
    mm_kernel<1, 64, 128, 0><<<dim3(512, 4), 256, 0, stream>>>(
        xb, wp1, b1, qkvs1, 512, 0, 0);
    attn1_kernel<<<NPIX / 4, 256, 0, stream>>>(qkvs1, hbuf);
    // proj2: [N][128] x [256][128]^T -> qkvs2 [N][256]
    mm_kernel<1, 128, 128, 0><<<dim3(512, 2), 256, 0, stream>>>(
        hbuf, wp2, b2, qkvs2, 256, 0, 0);
    attn2_kernel<<<NPIX / 8, 256, 0, stream>>>(qkvs2, xc);

    // conv1: im2col(xb, C=64) x [128][576]^T -> y1 [N][128], gelu
    mm_kernel<9, 64, 128, 0><<<dim3(512, 1), 256, 0, stream>>>(
        xb, wc1, cb1, y1, 128, 0, 1);
    // conv2: im2col(y1, C=128) x [64][1152]^T -> xc cols 0..63, gelu
    mm_kernel<9, 128, 64, 0><<<dim3(512, 1), 256, 0, stream>>>(
        y1, wc2, cb2, xc, 128, 0, 1);
    // conv3: im2col(xc, C=128) x [128][1152]^T -> t [N][128], gelu
    mm_kernel<9, 128, 128, 0><<<dim3(512, 1), 256, 0, stream>>>(
        xc, wf1, fb1, tbuf, 128, 0, 1);
    // conv4: im2col(t, C=128) x [64][1152]^T -> out f32 NCHW, gelu
    mm_kernel<9, 128, 64, 1><<<dim3(512, 1), 256, 0, stream>>>(
        tbuf, wf2, fb2, out, 0, 0, 1);
}

// Round 3
// 303.972 us; speedup vs baseline: 5.0797x; 1.7400x over previous
//
#include <hip/hip_runtime.h>
#include <hip/hip_bf16.h>

typedef unsigned int  u32;
typedef unsigned short u16;
typedef __attribute__((ext_vector_type(8))) short bf16x8;
typedef __attribute__((ext_vector_type(4))) float f32x4;

#define NPIX 65536

// ---------------- ws byte offsets ----------------
constexpr size_t SIG   = 0;                   // 4 floats
constexpr size_t B1OFF = 256;                 // 512 f32
constexpr size_t B2OFF = B1OFF + 2048;        // 256 f32
constexpr size_t WC1   = B2OFF + 1024;        // 128x576 bf16
constexpr size_t WC2   = WC1 + 147456;        // 64x1152
constexpr size_t WF1   = WC2 + 147456;        // 128x1152
constexpr size_t WF2   = WF1 + 294912;        // 64x1152
constexpr size_t WP1   = WF2 + 147456;        // 512x64
constexpr size_t WP2   = WP1 + 65536;         // 256x128
constexpr size_t XB    = WP2 + 65536;         // 65536x64 bf16 (8 MB)
constexpr size_t HBUF  = XB + 8388608;        // 65536x128 bf16 (16 MB)
constexpr size_t QKVS2 = HBUF + 16777216;     // 65536x256 bf16 (32 MB)
constexpr size_t XC    = QKVS2 + 33554432;    // 65536x128 bf16 (16 MB) concat buf
constexpr size_t QKVS1 = XC + 16777216;       // 65536x512 bf16 (64 MB)
constexpr size_t Y1    = QKVS1;               // alias: y1 lives after qkvs1 dead
constexpr size_t TBUF  = QKVS1 + 16777216;    // alias: t
constexpr size_t GRAM  = QKVS1 + 67108864;    // 4 x 128x128 f32 (256 KB)

// ---------------- helpers ----------------
__device__ __forceinline__ float gelu_f(float v) {
    return 0.5f * v * (1.0f + erff(v * 0.70710678118654752f));
}
__device__ __forceinline__ u16 f2bf(float f) {
    __hip_bfloat16 b = __float2bfloat16(f);
    return *reinterpret_cast<u16*>(&b);
}
__device__ __forceinline__ float blo(u32 u) {
    union { u32 i; float f; } x; x.i = u << 16; return x.f;
}
__device__ __forceinline__ float bhi(u32 u) {
    union { u32 i; float f; } x; x.i = u & 0xffff0000u; return x.f;
}
__device__ __forceinline__ void g2l16(const void* g, void* l) {
    __builtin_amdgcn_global_load_lds(
        (const __attribute__((address_space(1))) u32*)g,
        (__attribute__((address_space(3))) u32*)l, 16, 0, 0);
}

// ---------------- block reduction ----------------
__device__ float block_sum(float vv, float* red) {
    #pragma unroll
    for (int m = 1; m < 64; m <<= 1) vv += __shfl_xor(vv, m);
    int tid = threadIdx.x;
    __syncthreads();
    if ((tid & 63) == 0) red[tid >> 6] = vv;
    __syncthreads();
    return red[0] + red[1] + red[2] + red[3];
}

// ---------------- Gram matrix: G_w = W_w * W_w^T (tiled, parallel) ----------------
// 160 blocks: 64 tiles (cW1, 8x8) + 16 (cW2, 4x4) + 64 (fW1) + 16 (fW2)
__global__ __launch_bounds__(256)
void gram_kernel(const float* __restrict__ cW1, const float* __restrict__ cW2,
                 const float* __restrict__ fW1, const float* __restrict__ fW2,
                 float* __restrict__ Gall) {
    int bid = blockIdx.x;
    const float* W; int O, K, wsel, tile;
    if (bid < 64)       { W = cW1; O = 128; K = 576;  wsel = 0; tile = bid; }
    else if (bid < 80)  { W = cW2; O = 64;  K = 1152; wsel = 1; tile = bid - 64; }
    else if (bid < 144) { W = fW1; O = 128; K = 1152; wsel = 2; tile = bid - 80; }
    else                { W = fW2; O = 64;  K = 1152; wsel = 3; tile = bid - 144; }
    int ntiles = O >> 4;
    int ti0 = (tile / ntiles) << 4, tj0 = (tile % ntiles) << 4;
    __shared__ float Wi[16][33], Wj[16][33];
    int tid = threadIdx.x;
    int ti = tid >> 4, tj = tid & 15;
    int r = tid >> 5, c = tid & 31;
    float acc = 0.f;
    for (int k0 = 0; k0 < K; k0 += 32) {
        Wi[r][c]     = W[(size_t)(ti0 + r) * K + k0 + c];
        Wi[r + 8][c] = W[(size_t)(ti0 + r + 8) * K + k0 + c];
        Wj[r][c]     = W[(size_t)(tj0 + r) * K + k0 + c];
        Wj[r + 8][c] = W[(size_t)(tj0 + r + 8) * K + k0 + c];
        __syncthreads();
        #pragma unroll
        for (int k = 0; k < 32; ++k)
            acc += Wi[ti][k] * Wj[tj][k];
        __syncthreads();
    }
    Gall[wsel * 16384 + (ti0 + ti) * 128 + (tj0 + tj)] = acc;
}

// ---------------- power iteration on G (4 blocks) ----------------
// u_i = G u_{i-1} / ||G u_{i-1}||  (v-normalization cancels algebraically);
// sigma = ||G u2|| / sqrt(u2 . G u2)
__global__ __launch_bounds__(256)
void power_kernel(const float* __restrict__ Gall, float* __restrict__ sig) {
    int wsel = blockIdx.x;
    const float* G = Gall + wsel * 16384;
    const int O = (wsel == 0 || wsel == 2) ? 128 : 64;
    __shared__ float u[128], t[128], red[4];
    int tid = threadIdx.x;
    if (tid < O) u[tid] = 1.0f / sqrtf((float)O);
    __syncthreads();
    for (int it = 0; it < 3; ++it) {
        if (tid < O) {
            float s = 0.f;
            const float4* gr = reinterpret_cast<const float4*>(G + (size_t)tid * 128);
            for (int j = 0; j < O / 4; ++j) {
                float4 g = gr[j];
                s += g.x * u[4*j] + g.y * u[4*j+1] + g.z * u[4*j+2] + g.w * u[4*j+3];
            }
            t[tid] = s;
        }
        __syncthreads();
        float loc = (tid < O) ? t[tid] * t[tid] : 0.f;
        float nt = sqrtf(block_sum(loc, red));
        if (it == 2) {
            float locd = (tid < O) ? u[tid] * t[tid] : 0.f;
            float dot = block_sum(locd, red);
            if (tid == 0) sig[wsel] = nt / sqrtf(dot + 1e-24f);
        } else {
            if (tid < O) u[tid] = t[tid] / (nt + 1e-12f);
            __syncthreads();
        }
    }
}

// ---------------- conv weight prep: [O][C][3][3]/sigma -> bf16 [O][tap*C+ci] ----------------
__global__ __launch_bounds__(256)
void prep_conv_w(const float* __restrict__ cW1, const float* __restrict__ cW2,
                 const float* __restrict__ fW1, const float* __restrict__ fW2,
                 const float* __restrict__ sig,
                 u16* wc1, u16* wc2, u16* wf1, u16* wf2) {
    int wsel = blockIdx.y;
    const float* src; u16* dst; int O, C;
    switch (wsel) {
        case 0:  src = cW1; dst = wc1; O = 128; C = 64;  break;
        case 1:  src = cW2; dst = wc2; O = 64;  C = 128; break;
        case 2:  src = fW1; dst = wf1; O = 128; C = 128; break;
        default: src = fW2; dst = wf2; O = 64;  C = 128; break;
    }
    int idx = blockIdx.x * 256 + threadIdx.x;
    if (idx >= O * C * 9) return;
    int o = idx / (C * 9);
    int rem = idx - o * (C * 9);
    int ci = rem / 9, tap = rem - ci * 9;
    float v = src[idx] / sig[wsel];
    dst[(size_t)o * (C * 9) + tap * C + ci] = f2bf(v);
}

// ---------------- projection weight/bias prep (fused QKVS) ----------------
__global__ __launch_bounds__(256)
void prep_proj(const float* q1W, const float* k1W, const float* v1W, const float* s1W,
               const float* q2W, const float* k2W, const float* v2W, const float* s2W,
               const float* q1b, const float* k1b, const float* v1b, const float* s1b,
               const float* q2b, const float* k2b, const float* v2b, const float* s2b,
               u16* wp1, u16* wp2, float* b1, float* b2) {
    const float* W1[4] = {q1W, k1W, v1W, s1W};
    const float* W2[4] = {q2W, k2W, v2W, s2W};
    const float* Bb1[4] = {q1b, k1b, v1b, s1b};
    const float* Bb2[4] = {q2b, k2b, v2b, s2b};
    int idx = blockIdx.x * 256 + threadIdx.x;
    if (idx < 32768) {
        int w = idx >> 13, r = idx & 8191;       // [128][64] contiguous
        wp1[(size_t)w * 8192 + r] = f2bf(W1[w][r]);
    } else if (idx < 65536) {
        int j = idx - 32768; int w = j >> 13, r = j & 8191;  // [64][128]
        wp2[(size_t)w * 8192 + r] = f2bf(W2[w][r]);
    } else if (idx < 66048) {
        int j = idx - 65536; int w = j >> 7; b1[j] = Bb1[w][j & 127];
    } else if (idx < 66304) {
        int j = idx - 66048; int w = j >> 6; b2[j] = Bb2[w][j & 63];
    }
}

// ---------------- x NCHW f32 -> [pix][64] bf16 ----------------
__global__ __launch_bounds__(256)
void convert_x(const float* __restrict__ x, u16* __restrict__ xb) {
    __shared__ float tile[64][65];
    int b = blockIdx.x >> 6, y = blockIdx.x & 63;
    int tid = threadIdx.x;
    #pragma unroll
    for (int i = 0; i < 16; ++i) {
        int c = (tid >> 6) + i * 4;
        tile[c][tid & 63] = x[(((size_t)b * 64 + c) << 12) + (y << 6) + (tid & 63)];
    }
    __syncthreads();
    #pragma unroll
    for (int i = 0; i < 16; ++i) {
        int idx = tid + i * 256;
        int p = idx >> 6, c = idx & 63;
        xb[(((size_t)b << 12) + (y << 6) + p) * 64 + c] = f2bf(tile[c][p]);
    }
}

// ---------------- bf16 MFMA GEMM, implicit im2col (edge-clamped 3x3) ----------------
// A: [NPIX][CC] bf16 activations. Bw: [N][K] bf16 (K = CC*TAPS, tap-major).
// OUTM 0: bf16 out at Cout[m*ostride + ocol0 + n]; OUTM 1: f32 NCHW out.
template<int TAPS, int CC, int BN, int OUTM>
__global__ __launch_bounds__(256)
void mm_kernel(const u16* __restrict__ A, const u16* __restrict__ Bw,
               const float* __restrict__ bias, void* __restrict__ Cout,
               int ostride, int ocol0, int do_gelu) {
    constexpr int K = CC * TAPS;
    constexpr int NSTEP = K / 32;
    constexpr int NF = BN / 32;
    constexpr int HN = BN / 2;
    __shared__ u16 Als[128 * 32];
    __shared__ u16 Bls[BN * 32];
    const int tid = threadIdx.x;
    const int w = tid >> 6;
    const int lane = tid & 63;
    const int m0 = blockIdx.x * 128;
    const int nt0 = blockIdx.y * BN;
    const int wm = w >> 1, wn = w & 1;

    f32x4 acc[4][NF];
    #pragma unroll
    for (int i = 0; i < 4; ++i)
        #pragma unroll
        for (int j = 0; j < NF; ++j) {
            f32x4 z = {0.f, 0.f, 0.f, 0.f};
            acc[i][j] = z;
        }

    #pragma unroll 2
    for (int kt = 0; kt < NSTEP; ++kt) {
        const int kk = kt * 32;
        int tap = 0, ci0 = kk;
        if (TAPS == 9) { tap = kk / CC; ci0 = kk - tap * CC; }
        const int dy = tap / 3 - 1, dx2 = tap % 3 - 1;
        // stage A tile [128][32]
        #pragma unroll
        for (int r = 0; r < 2; ++r) {
            int row = (tid >> 2) + r * 64;
            int m = m0 + row;
            int q;
            if (TAPS == 9) {
                int yy = ((m >> 6) & 63) + dy; yy = yy < 0 ? 0 : (yy > 63 ? 63 : yy);
                int xx = (m & 63) + dx2;       xx = xx < 0 ? 0 : (xx > 63 ? 63 : xx);
                q = (m & ~4095) | (yy << 6) | xx;
            } else q = m;
            const u16* g = A + (size_t)q * CC + ci0 + (tid & 3) * 8;
            g2l16(g, &Als[w * 512 + r * 2048]);
        }
        // stage B tile [BN][32]  (Bw rows are K-contiguous)
        #pragma unroll
        for (int r = 0; r < BN / 64; ++r) {
            int row = (tid >> 2) + r * 64;
            const u16* g = Bw + (size_t)(nt0 + row) * K + kk + (tid & 3) * 8;
            g2l16(g, &Bls[w * 512 + r * 2048]);
        }
        __syncthreads();
        bf16x8 af[4];
        #pragma unroll
        for (int mf = 0; mf < 4; ++mf)
            af[mf] = *reinterpret_cast<const bf16x8*>(
                &Als[(wm * 64 + mf * 16 + (lane & 15)) * 32 + (lane >> 4) * 8]);
        #pragma unroll
        for (int nf = 0; nf < NF; ++nf) {
            bf16x8 bfv = *reinterpret_cast<const bf16x8*>(
                &Bls[(wn * HN + nf * 16 + (lane & 15)) * 32 + (lane >> 4) * 8]);
            #pragma unroll
            for (int mf = 0; mf < 4; ++mf)
                acc[mf][nf] = __builtin_amdgcn_mfma_f32_16x16x32_bf16(
                    af[mf], bfv, acc[mf][nf], 0, 0, 0);
        }
        __syncthreads();
    }

    // epilogue
    #pragma unroll
    for (int mf = 0; mf < 4; ++mf) {
        int mrow = m0 + wm * 64 + mf * 16 + (lane >> 4) * 4;
        #pragma unroll
        for (int nf = 0; nf < NF; ++nf) {
            int col = nt0 + wn * HN + nf * 16 + (lane & 15);
            float bv = bias[col];
            if (OUTM == 0) {
                u16* Co = (u16*)Cout;
                #pragma unroll
                for (int j = 0; j < 4; ++j) {
                    float v = acc[mf][nf][j] + bv;
                    if (do_gelu) v = gelu_f(v);
                    Co[(size_t)(mrow + j) * ostride + ocol0 + col] = f2bf(v);
                }
            } else {
                float* Co = (float*)Cout;
                int b = m0 >> 12;
                int pixb = (mrow & 4095);
                f32x4 vv;
                #pragma unroll
                for (int j = 0; j < 4; ++j) {
                    float v = acc[mf][nf][j] + bv;
                    vv[j] = gelu_f(v);
                }
                *reinterpret_cast<f32x4*>(&Co[((size_t)(b * 64 + col)) * 4096 + pixb]) = vv;
            }
        }
    }
}

// ---------------- attention layer 1: heads=8, d=16 ----------------
__global__ __launch_bounds__(256)
void attn1_kernel(const u16* __restrict__ qkvs, u16* __restrict__ h) {
    int wid = threadIdx.x >> 6, lane = threadIdx.x & 63;
    int n = blockIdx.x * 4 + wid;
    int y = (n >> 6) & 63, x = n & 63;
    u32 qp = ((const u32*)(qkvs + (size_t)n * 512))[lane];
    float q0 = blo(qp), q1 = bhi(qp);
    float al[9], mx = -1e30f;
    #pragma unroll
    for (int e = 0; e < 9; ++e) {
        int dy = e / 3 - 1, dx = e % 3 - 1;
        if ((unsigned)(y + dy) < 64u && (unsigned)(x + dx) < 64u) {
            u32 kp = ((const u32*)(qkvs + (size_t)(n + dy * 64 + dx) * 512 + 128))[lane];
            float p = q0 * blo(kp) + q1 * bhi(kp);
            p += __shfl_xor(p, 1); p += __shfl_xor(p, 2); p += __shfl_xor(p, 4);
            al[e] = p * 0.25f;
            mx = fmaxf(mx, al[e]);
        } else al[e] = -1e30f;
    }
    float s = 0.f;
    #pragma unroll
    for (int e = 0; e < 9; ++e) { al[e] = expf(al[e] - mx); s += al[e]; }
    float o0 = 0.f, o1 = 0.f;
    #pragma unroll
    for (int e = 0; e < 9; ++e) {
        int dy = e / 3 - 1, dx = e % 3 - 1;
        if ((unsigned)(y + dy) < 64u && (unsigned)(x + dx) < 64u) {
            u32 vp = ((const u32*)(qkvs + (size_t)(n + dy * 64 + dx) * 512 + 256))[lane];
            o0 += al[e] * blo(vp); o1 += al[e] * bhi(vp);
        }
    }
    float r = 1.f / (s + 1e-16f);
    u32 sp = ((const u32*)(qkvs + (size_t)n * 512 + 384))[lane];
    float h0 = gelu_f(o0 * r + blo(sp));
    float h1 = gelu_f(o1 * r + bhi(sp));
    ((u32*)(h + (size_t)n * 128))[lane] = (u32)f2bf(h0) | ((u32)f2bf(h1) << 16);
}

// ---------------- attention layer 2: heads=1, d=64 -> xc cols 64..127 ----------------
__global__ __launch_bounds__(256)
void attn2_kernel(const u16* __restrict__ qkvs, u16* __restrict__ xc) {
    int sub = threadIdx.x >> 5, hl = threadIdx.x & 31;
    int n = blockIdx.x * 8 + sub;
    int y = (n >> 6) & 63, x = n & 63;
    u32 qp = ((const u32*)(qkvs + (size_t)n * 256))[hl];
    float q0 = blo(qp), q1 = bhi(qp);
    float al[9], mx = -1e30f;
    #pragma unroll
    for (int e = 0; e < 9; ++e) {
        int dy = e / 3 - 1, dx = e % 3 - 1;
        if ((unsigned)(y + dy) < 64u && (unsigned)(x + dx) < 64u) {
            u32 kp = ((const u32*)(qkvs + (size_t)(n + dy * 64 + dx) * 256 + 64))[hl];
            float p = q0 * blo(kp) + q1 * bhi(kp);
            p += __shfl_xor(p, 1); p += __shfl_xor(p, 2); p += __shfl_xor(p, 4);
            p += __shfl_xor(p, 8); p += __shfl_xor(p, 16);
            al[e] = p * 0.125f;
            mx = fmaxf(mx, al[e]);
        } else al[e] = -1e30f;
    }
    float s = 0.f;
    #pragma unroll
    for (int e = 0; e < 9; ++e) { al[e] = expf(al[e] - mx); s += al[e]; }
    float o0 = 0.f, o1 = 0.f;
    #pragma unroll
    for (int e = 0; e < 9; ++e) {
        int dy = e / 3 - 1, dx = e % 3 - 1;
        if ((unsigned)(y + dy) < 64u && (unsigned)(x + dx) < 64u) {
            u32 vp = ((const u32*)(qkvs + (size_t)(n + dy * 64 + dx) * 256 + 128))[hl];
            o0 += al[e] * blo(vp); o1 += al[e] * bhi(vp);
        }
    }
    float r = 1.f / (s + 1e-16f);
    u32 sp = ((const u32*)(qkvs + (size_t)n * 256 + 192))[hl];
    float h0 = gelu_f(o0 * r + blo(sp));
    float h1 = gelu_f(o1 * r + bhi(sp));
    ((u32*)(xc + (size_t)n * 128 + 64))[hl] = (u32)f2bf(h0) | ((u32)f2bf(h1) << 16);
}

// ---------------- host launcher ----------------
extern "C" void kernel_launch(void* const* d_in, const int* in_sizes, int n_in,
                              void* d_out, int out_size, void* d_ws, size_t ws_size,
                              hipStream_t stream) {
    const float* x   = (const float*)d_in[0];
    const float* cW1 = (const float*)d_in[1];
    const float* cb1 = (const float*)d_in[2];
    const float* cW2 = (const float*)d_in[3];
    const float* cb2 = (const float*)d_in[4];
    const float* q1W = (const float*)d_in[5];
    const float* q1b = (const float*)d_in[6];
    const float* k1W = (const float*)d_in[7];
    const float* k1b = (const float*)d_in[8];
    const float* v1W = (const float*)d_in[9];
    const float* v1b = (const float*)d_in[10];
    const float* s1W = (const float*)d_in[11];
    const float* s1b = (const float*)d_in[12];
    const float* q2W = (const float*)d_in[13];
    const float* q2b = (const float*)d_in[14];
    const float* k2W = (const float*)d_in[15];
    const float* k2b = (const float*)d_in[16];
    const float* v2W = (const float*)d_in[17];
    const float* v2b = (const float*)d_in[18];
    const float* s2W = (const float*)d_in[19];
    const float* s2b = (const float*)d_in[20];
    const float* fW1 = (const float*)d_in[21];
    const float* fb1 = (const float*)d_in[22];
    const float* fW2 = (const float*)d_in[23];
    const float* fb2 = (const float*)d_in[24];

    char* ws = (char*)d_ws;
    float* sig  = (float*)(ws + SIG);
    float* b1   = (float*)(ws + B1OFF);
    float* b2   = (float*)(ws + B2OFF);
    u16* wc1    = (u16*)(ws + WC1);
    u16* wc2    = (u16*)(ws + WC2);
    u16* wf1    = (u16*)(ws + WF1);
    u16* wf2    = (u16*)(ws + WF2);
    u16* wp1    = (u16*)(ws + WP1);
    u16* wp2    = (u16*)(ws + WP2);
    u16* xb     = (u16*)(ws + XB);
    u16* hbuf   = (u16*)(ws + HBUF);
    u16* qkvs2  = (u16*)(ws + QKVS2);
    u16* xc     = (u16*)(ws + XC);
    u16* qkvs1  = (u16*)(ws + QKVS1);
    u16* y1     = (u16*)(ws + Y1);
    u16* tbuf   = (u16*)(ws + TBUF);
    float* gram = (float*)(ws + GRAM);
    float* out  = (float*)d_out;

    // spectral norm via Gram matrix (parallel) + tiny power iteration
    gram_kernel<<<160, 256, 0, stream>>>(cW1, cW2, fW1, fW2, gram);
    power_kernel<<<4, 256, 0, stream>>>(gram, sig);
    prep_conv_w<<<dim3(576, 4), 256, 0, stream>>>(cW1, cW2, fW1, fW2, sig,
                                                  wc1, wc2, wf1, wf2);
    prep_proj<<<260, 256, 0, stream>>>(q1W, k1W, v1W, s1W, q2W, k2W, v2W, s2W,
                                       q1b, k1b, v1b, s1b, q2b, k2b, v2b, s2b,
                                       wp1, wp2, b1, b2);
    convert_x<<<1024, 256, 0, stream>>>(x, xb);

    // proj1: [N][64] x [512][64]^T -> qkvs1 [N][512]
    mm_kernel<1, 64, 128, 0><<<dim3(512, 4), 256, 0, stream>>>(
        xb, wp1, b1, qkvs1, 512, 0, 0);
    attn1_kernel<<<NPIX / 4, 256, 0, stream>>>(qkvs1, hbuf);
    // proj2: [N][128] x [256][128]^T -> qkvs2 [N][256]
    mm_kernel<1, 128, 128, 0><<<dim3(512, 2), 256, 0, stream>>>(
        hbuf, wp2, b2, qkvs2, 256, 0, 0);
    attn2_kernel<<<NPIX / 8, 256, 0, stream>>>(qkvs2, xc);

    // conv1: im2col(xb, C=64) x [128][576]^T -> y1 [N][128], gelu
    mm_kernel<9, 64, 128, 0><<<dim3(512, 1), 256, 0, stream>>>(
        xb, wc1, cb1, y1, 128, 0, 1);
    // conv2: im2col(y1, C=128) x [64][1152]^T -> xc cols 0..63, gelu
    mm_kernel<9, 128, 64, 0><<<dim3(512, 1), 256, 0, stream>>>(
        y1, wc2, cb2, xc, 128, 0, 1);
    // conv3: im2col(xc, C=128) x [128][1152]^T -> t [N][128], gelu
    mm_kernel<9, 128, 128, 0><<<dim3(512, 1), 256, 0, stream>>>(
        xc, wf1, fb1, tbuf, 128, 0, 1);
    // conv4: im2col(t, C=128) x [64][1152]^T -> out f32 NCHW, gelu
    mm_kernel<9, 128, 64, 1><<<dim3(512, 1), 256, 0, stream>>>(
        tbuf, wf2, fb2, out, 0, 0, 1);
}

// Round 4
// 235.774 us; speedup vs baseline: 6.5491x; 1.2893x over previous
//
#include <hip/hip_runtime.h>
#include <hip/hip_bf16.h>

typedef unsigned int  u32;
typedef unsigned short u16;
typedef __attribute__((ext_vector_type(8))) short bf16x8;
typedef __attribute__((ext_vector_type(4))) float f32x4;
typedef __attribute__((ext_vector_type(4))) u32 u32x4;

#define NPIX 65536

// ---------------- ws byte offsets ----------------
constexpr size_t SIG   = 0;                   // 4 floats
constexpr size_t B1OFF = 256;                 // 512 f32
constexpr size_t B2OFF = B1OFF + 2048;        // 256 f32
constexpr size_t WC1   = B2OFF + 1024;        // 128x576 bf16
constexpr size_t WC2   = WC1 + 147456;        // 64x1152
constexpr size_t WF1   = WC2 + 147456;        // 128x1152
constexpr size_t WF2   = WF1 + 294912;        // 64x1152
constexpr size_t WP1   = WF2 + 147456;        // 512x64
constexpr size_t WP2   = WP1 + 65536;         // 256x128
constexpr size_t XB    = WP2 + 65536;         // 65536x64 bf16 (8 MB)
constexpr size_t HBUF  = XB + 8388608;        // 65536x128 bf16 (16 MB)
constexpr size_t QKVS2 = HBUF + 16777216;     // 65536x256 bf16 (32 MB)
constexpr size_t XC    = QKVS2 + 33554432;    // 65536x128 bf16 (16 MB) concat buf
constexpr size_t QKVS1 = XC + 16777216;       // 65536x512 bf16 (64 MB)
constexpr size_t Y1    = QKVS1;               // alias: y1 lives after qkvs1 dead
constexpr size_t TBUF  = QKVS1 + 16777216;    // alias: t
constexpr size_t GRAM  = QKVS1 + 67108864;    // 4 x 128x128 f32 (256 KB)

// ---------------- helpers ----------------
__device__ __forceinline__ float gelu_f(float v) {
    // exact-erf gelu, A&S 7.1.26 minimax (|erf err| <= 1.5e-7), branchless
    float xa = fabsf(v) * 0.70710678118654752f;
    float t  = __fdividef(1.0f, fmaf(0.3275911f, xa, 1.0f));
    float poly = t * fmaf(t, fmaf(t, fmaf(t, fmaf(t, 1.061405429f, -1.453152027f),
                   1.421413741f), -0.284496736f), 0.254829592f);
    float erfv = 1.0f - poly * __expf(-xa * xa);
    erfv = copysignf(erfv, v);
    return 0.5f * v * (1.0f + erfv);
}
__device__ __forceinline__ u16 f2bf(float f) {
    __hip_bfloat16 b = __float2bfloat16(f);
    return *reinterpret_cast<u16*>(&b);
}
__device__ __forceinline__ float blo(u32 u) {
    union { u32 i; float f; } x; x.i = u << 16; return x.f;
}
__device__ __forceinline__ float bhi(u32 u) {
    union { u32 i; float f; } x; x.i = u & 0xffff0000u; return x.f;
}
__device__ __forceinline__ u32 packbf(float a, float b) {
    return (u32)f2bf(a) | ((u32)f2bf(b) << 16);
}
__device__ __forceinline__ void g2l16(const void* g, void* l) {
    __builtin_amdgcn_global_load_lds(
        (const __attribute__((address_space(1))) u32*)g,
        (__attribute__((address_space(3))) u32*)l, 16, 0, 0);
}

// ---------------- block reduction ----------------
__device__ float block_sum(float vv, float* red) {
    #pragma unroll
    for (int m = 1; m < 64; m <<= 1) vv += __shfl_xor(vv, m);
    int tid = threadIdx.x;
    __syncthreads();
    if ((tid & 63) == 0) red[tid >> 6] = vv;
    __syncthreads();
    return red[0] + red[1] + red[2] + red[3];
}

// ---------------- Gram matrix: G_w = W_w * W_w^T (tiled, parallel) ----------------
__global__ __launch_bounds__(256)
void gram_kernel(const float* __restrict__ cW1, const float* __restrict__ cW2,
                 const float* __restrict__ fW1, const float* __restrict__ fW2,
                 float* __restrict__ Gall) {
    int bid = blockIdx.x;
    const float* W; int O, K, wsel, tile;
    if (bid < 64)       { W = cW1; O = 128; K = 576;  wsel = 0; tile = bid; }
    else if (bid < 80)  { W = cW2; O = 64;  K = 1152; wsel = 1; tile = bid - 64; }
    else if (bid < 144) { W = fW1; O = 128; K = 1152; wsel = 2; tile = bid - 80; }
    else                { W = fW2; O = 64;  K = 1152; wsel = 3; tile = bid - 144; }
    int ntiles = O >> 4;
    int ti0 = (tile / ntiles) << 4, tj0 = (tile % ntiles) << 4;
    __shared__ float Wi[16][33], Wj[16][33];
    int tid = threadIdx.x;
    int ti = tid >> 4, tj = tid & 15;
    int r = tid >> 5, c = tid & 31;
    float acc = 0.f;
    for (int k0 = 0; k0 < K; k0 += 32) {
        Wi[r][c]     = W[(size_t)(ti0 + r) * K + k0 + c];
        Wi[r + 8][c] = W[(size_t)(ti0 + r + 8) * K + k0 + c];
        Wj[r][c]     = W[(size_t)(tj0 + r) * K + k0 + c];
        Wj[r + 8][c] = W[(size_t)(tj0 + r + 8) * K + k0 + c];
        __syncthreads();
        #pragma unroll
        for (int k = 0; k < 32; ++k)
            acc += Wi[ti][k] * Wj[tj][k];
        __syncthreads();
    }
    Gall[wsel * 16384 + (ti0 + ti) * 128 + (tj0 + tj)] = acc;
}

// ---------------- power iteration on G (4 blocks) ----------------
__global__ __launch_bounds__(256)
void power_kernel(const float* __restrict__ Gall, float* __restrict__ sig) {
    int wsel = blockIdx.x;
    const float* G = Gall + wsel * 16384;
    const int O = (wsel == 0 || wsel == 2) ? 128 : 64;
    __shared__ float u[128], t[128], red[4];
    int tid = threadIdx.x;
    if (tid < O) u[tid] = 1.0f / sqrtf((float)O);
    __syncthreads();
    for (int it = 0; it < 3; ++it) {
        if (tid < O) {
            float s = 0.f;
            const float4* gr = reinterpret_cast<const float4*>(G + (size_t)tid * 128);
            for (int j = 0; j < O / 4; ++j) {
                float4 g = gr[j];
                s += g.x * u[4*j] + g.y * u[4*j+1] + g.z * u[4*j+2] + g.w * u[4*j+3];
            }
            t[tid] = s;
        }
        __syncthreads();
        float loc = (tid < O) ? t[tid] * t[tid] : 0.f;
        float nt = sqrtf(block_sum(loc, red));
        if (it == 2) {
            float locd = (tid < O) ? u[tid] * t[tid] : 0.f;
            float dot = block_sum(locd, red);
            if (tid == 0) sig[wsel] = nt / sqrtf(dot + 1e-24f);
        } else {
            if (tid < O) u[tid] = t[tid] / (nt + 1e-12f);
            __syncthreads();
        }
    }
}

// ---------------- conv weight prep ----------------
__global__ __launch_bounds__(256)
void prep_conv_w(const float* __restrict__ cW1, const float* __restrict__ cW2,
                 const float* __restrict__ fW1, const float* __restrict__ fW2,
                 const float* __restrict__ sig,
                 u16* wc1, u16* wc2, u16* wf1, u16* wf2) {
    int wsel = blockIdx.y;
    const float* src; u16* dst; int O, C;
    switch (wsel) {
        case 0:  src = cW1; dst = wc1; O = 128; C = 64;  break;
        case 1:  src = cW2; dst = wc2; O = 64;  C = 128; break;
        case 2:  src = fW1; dst = wf1; O = 128; C = 128; break;
        default: src = fW2; dst = wf2; O = 64;  C = 128; break;
    }
    int idx = blockIdx.x * 256 + threadIdx.x;
    if (idx >= O * C * 9) return;
    int o = idx / (C * 9);
    int rem = idx - o * (C * 9);
    int ci = rem / 9, tap = rem - ci * 9;
    float v = src[idx] / sig[wsel];
    dst[(size_t)o * (C * 9) + tap * C + ci] = f2bf(v);
}

// ---------------- projection weight/bias prep ----------------
__global__ __launch_bounds__(256)
void prep_proj(const float* q1W, const float* k1W, const float* v1W, const float* s1W,
               const float* q2W, const float* k2W, const float* v2W, const float* s2W,
               const float* q1b, const float* k1b, const float* v1b, const float* s1b,
               const float* q2b, const float* k2b, const float* v2b, const float* s2b,
               u16* wp1, u16* wp2, float* b1, float* b2) {
    const float* W1[4] = {q1W, k1W, v1W, s1W};
    const float* W2[4] = {q2W, k2W, v2W, s2W};
    const float* Bb1[4] = {q1b, k1b, v1b, s1b};
    const float* Bb2[4] = {q2b, k2b, v2b, s2b};
    int idx = blockIdx.x * 256 + threadIdx.x;
    if (idx < 32768) {
        int w = idx >> 13, r = idx & 8191;
        wp1[(size_t)w * 8192 + r] = f2bf(W1[w][r]);
    } else if (idx < 65536) {
        int j = idx - 32768; int w = j >> 13, r = j & 8191;
        wp2[(size_t)w * 8192 + r] = f2bf(W2[w][r]);
    } else if (idx < 66048) {
        int j = idx - 65536; int w = j >> 7; b1[j] = Bb1[w][j & 127];
    } else if (idx < 66304) {
        int j = idx - 66048; int w = j >> 6; b2[j] = Bb2[w][j & 63];
    }
}

// ---------------- x NCHW f32 -> [pix][64] bf16 ----------------
__global__ __launch_bounds__(256)
void convert_x(const float* __restrict__ x, u16* __restrict__ xb) {
    __shared__ float tile[64][65];
    int b = blockIdx.x >> 6, y = blockIdx.x & 63;
    int tid = threadIdx.x;
    #pragma unroll
    for (int i = 0; i < 16; ++i) {
        int c = (tid >> 6) + i * 4;
        tile[c][tid & 63] = x[(((size_t)b * 64 + c) << 12) + (y << 6) + (tid & 63)];
    }
    __syncthreads();
    #pragma unroll
    for (int i = 0; i < 16; ++i) {
        int idx = tid + i * 256;
        int p = idx >> 6, c = idx & 63;
        xb[(((size_t)b << 12) + (y << 6) + p) * 64 + c] = f2bf(tile[c][p]);
    }
}

// ---------------- bf16 MFMA GEMM, implicit im2col ----------------
template<int TAPS, int CC, int BN, int OUTM>
__global__ __launch_bounds__(256)
void mm_kernel(const u16* __restrict__ A, const u16* __restrict__ Bw,
               const float* __restrict__ bias, void* __restrict__ Cout,
               int ostride, int ocol0, int do_gelu) {
    constexpr int K = CC * TAPS;
    constexpr int NSTEP = K / 32;
    constexpr int NF = BN / 32;
    constexpr int HN = BN / 2;
    __shared__ u16 Als[128 * 32];
    __shared__ u16 Bls[BN * 32];
    const int tid = threadIdx.x;
    const int w = tid >> 6;
    const int lane = tid & 63;
    const int m0 = blockIdx.x * 128;
    const int nt0 = blockIdx.y * BN;
    const int wm = w >> 1, wn = w & 1;

    f32x4 acc[4][NF];
    #pragma unroll
    for (int i = 0; i < 4; ++i)
        #pragma unroll
        for (int j = 0; j < NF; ++j) {
            f32x4 z = {0.f, 0.f, 0.f, 0.f};
            acc[i][j] = z;
        }

    #pragma unroll 2
    for (int kt = 0; kt < NSTEP; ++kt) {
        const int kk = kt * 32;
        int tap = 0, ci0 = kk;
        if (TAPS == 9) { tap = kk / CC; ci0 = kk - tap * CC; }
        const int dy = tap / 3 - 1, dx2 = tap % 3 - 1;
        #pragma unroll
        for (int r = 0; r < 2; ++r) {
            int row = (tid >> 2) + r * 64;
            int m = m0 + row;
            int q;
            if (TAPS == 9) {
                int yy = ((m >> 6) & 63) + dy; yy = yy < 0 ? 0 : (yy > 63 ? 63 : yy);
                int xx = (m & 63) + dx2;       xx = xx < 0 ? 0 : (xx > 63 ? 63 : xx);
                q = (m & ~4095) | (yy << 6) | xx;
            } else q = m;
            const u16* g = A + (size_t)q * CC + ci0 + (tid & 3) * 8;
            g2l16(g, &Als[w * 512 + r * 2048]);
        }
        #pragma unroll
        for (int r = 0; r < BN / 64; ++r) {
            int row = (tid >> 2) + r * 64;
            const u16* g = Bw + (size_t)(nt0 + row) * K + kk + (tid & 3) * 8;
            g2l16(g, &Bls[w * 512 + r * 2048]);
        }
        __syncthreads();
        bf16x8 af[4];
        #pragma unroll
        for (int mf = 0; mf < 4; ++mf)
            af[mf] = *reinterpret_cast<const bf16x8*>(
                &Als[(wm * 64 + mf * 16 + (lane & 15)) * 32 + (lane >> 4) * 8]);
        #pragma unroll
        for (int nf = 0; nf < NF; ++nf) {
            bf16x8 bfv = *reinterpret_cast<const bf16x8*>(
                &Bls[(wn * HN + nf * 16 + (lane & 15)) * 32 + (lane >> 4) * 8]);
            #pragma unroll
            for (int mf = 0; mf < 4; ++mf)
                acc[mf][nf] = __builtin_amdgcn_mfma_f32_16x16x32_bf16(
                    af[mf], bfv, acc[mf][nf], 0, 0, 0);
        }
        __syncthreads();
    }

    #pragma unroll
    for (int mf = 0; mf < 4; ++mf) {
        int mrow = m0 + wm * 64 + mf * 16 + (lane >> 4) * 4;
        #pragma unroll
        for (int nf = 0; nf < NF; ++nf) {
            int col = nt0 + wn * HN + nf * 16 + (lane & 15);
            float bv = bias[col];
            if (OUTM == 0) {
                u16* Co = (u16*)Cout;
                #pragma unroll
                for (int j = 0; j < 4; ++j) {
                    float v = acc[mf][nf][j] + bv;
                    if (do_gelu) v = gelu_f(v);
                    Co[(size_t)(mrow + j) * ostride + ocol0 + col] = f2bf(v);
                }
            } else {
                float* Co = (float*)Cout;
                int b = m0 >> 12;
                int pixb = (mrow & 4095);
                f32x4 vv;
                #pragma unroll
                for (int j = 0; j < 4; ++j) {
                    float v = acc[mf][nf][j] + bv;
                    vv[j] = gelu_f(v);
                }
                *reinterpret_cast<f32x4*>(&Co[((size_t)(b * 64 + col)) * 4096 + pixb]) = vv;
            }
        }
    }
}

// ---------------- attention layer 1: heads=8, d=16, 8ch/lane ----------------
// qkvs row = 256 u32 (Q 0..63, K 64..127, V 128..191, S 192..255)
__global__ __launch_bounds__(256)
void attn1_kernel(const u16* __restrict__ qkvs, u16* __restrict__ h) {
    const int tid = threadIdx.x;
    const int l16 = tid & 15;
    const int n = blockIdx.x * 16 + (tid >> 4);
    const int y = (n >> 6) & 63, x = n & 63;
    const u32* qk = (const u32*)qkvs;
    const int nbase = (n << 8) + l16 * 4;

    u32x4 qp = *(const u32x4*)(qk + nbase);
    float q[8];
    #pragma unroll
    for (int i = 0; i < 4; ++i) { q[2*i] = blo(qp[i]); q[2*i+1] = bhi(qp[i]); }

    float al[9];
    float mx = -1e30f;
    #pragma unroll
    for (int e = 0; e < 9; ++e) {
        const int dy = e / 3 - 1, dx = e % 3 - 1;
        const bool valid = (unsigned)(y + dy) < 64u && (unsigned)(x + dx) < 64u;
        const int off = valid ? ((dy * 64 + dx) << 8) : 0;
        u32x4 kp = *(const u32x4*)(qk + nbase + off + 64);
        float p = 0.f;
        #pragma unroll
        for (int i = 0; i < 4; ++i) {
            p = fmaf(q[2*i],   blo(kp[i]), p);
            p = fmaf(q[2*i+1], bhi(kp[i]), p);
        }
        p += __shfl_xor(p, 1);       // head = 16ch = 2 lanes
        al[e] = valid ? p * 0.25f : -1e30f;
        mx = fmaxf(mx, al[e]);
    }
    float s = 0.f;
    #pragma unroll
    for (int e = 0; e < 9; ++e) { al[e] = __expf(al[e] - mx); s += al[e]; }

    float o[8] = {0.f, 0.f, 0.f, 0.f, 0.f, 0.f, 0.f, 0.f};
    #pragma unroll
    for (int e = 0; e < 9; ++e) {
        const int dy = e / 3 - 1, dx = e % 3 - 1;
        const bool valid = (unsigned)(y + dy) < 64u && (unsigned)(x + dx) < 64u;
        const int off = valid ? ((dy * 64 + dx) << 8) : 0;
        u32x4 vp = *(const u32x4*)(qk + nbase + off + 128);
        const float a = al[e];
        #pragma unroll
        for (int i = 0; i < 4; ++i) {
            o[2*i]   = fmaf(a, blo(vp[i]), o[2*i]);
            o[2*i+1] = fmaf(a, bhi(vp[i]), o[2*i+1]);
        }
    }
    const float r = __fdividef(1.0f, s + 1e-16f);
    u32x4 sp = *(const u32x4*)(qk + nbase + 192);
    u32x4 res;
    #pragma unroll
    for (int i = 0; i < 4; ++i) {
        float h0 = gelu_f(fmaf(o[2*i],   r, blo(sp[i])));
        float h1 = gelu_f(fmaf(o[2*i+1], r, bhi(sp[i])));
        res[i] = packbf(h0, h1);
    }
    *(u32x4*)((u32*)h + (n << 6) + l16 * 4) = res;
}

// ---------------- attention layer 2: heads=1, d=64, 8ch/lane ----------------
// qkvs row = 128 u32 (Q 0..31, K 32..63, V 64..95, S 96..127); out -> xc cols 64..127
__global__ __launch_bounds__(256)
void attn2_kernel(const u16* __restrict__ qkvs, u16* __restrict__ xc) {
    const int tid = threadIdx.x;
    const int l8 = tid & 7;
    const int n = blockIdx.x * 32 + (tid >> 3);
    const int y = (n >> 6) & 63, x = n & 63;
    const u32* qk = (const u32*)qkvs;
    const int nbase = (n << 7) + l8 * 4;

    u32x4 qp = *(const u32x4*)(qk + nbase);
    float q[8];
    #pragma unroll
    for (int i = 0; i < 4; ++i) { q[2*i] = blo(qp[i]); q[2*i+1] = bhi(qp[i]); }

    float al[9];
    float mx = -1e30f;
    #pragma unroll
    for (int e = 0; e < 9; ++e) {
        const int dy = e / 3 - 1, dx = e % 3 - 1;
        const bool valid = (unsigned)(y + dy) < 64u && (unsigned)(x + dx) < 64u;
        const int off = valid ? ((dy * 64 + dx) << 7) : 0;
        u32x4 kp = *(const u32x4*)(qk + nbase + off + 32);
        float p = 0.f;
        #pragma unroll
        for (int i = 0; i < 4; ++i) {
            p = fmaf(q[2*i],   blo(kp[i]), p);
            p = fmaf(q[2*i+1], bhi(kp[i]), p);
        }
        p += __shfl_xor(p, 1);
        p += __shfl_xor(p, 2);
        p += __shfl_xor(p, 4);       // head = 64ch = 8 lanes
        al[e] = valid ? p * 0.125f : -1e30f;
        mx = fmaxf(mx, al[e]);
    }
    float s = 0.f;
    #pragma unroll
    for (int e = 0; e < 9; ++e) { al[e] = __expf(al[e] - mx); s += al[e]; }

    float o[8] = {0.f, 0.f, 0.f, 0.f, 0.f, 0.f, 0.f, 0.f};
    #pragma unroll
    for (int e = 0; e < 9; ++e) {
        const int dy = e / 3 - 1, dx = e % 3 - 1;
        const bool valid = (unsigned)(y + dy) < 64u && (unsigned)(x + dx) < 64u;
        const int off = valid ? ((dy * 64 + dx) << 7) : 0;
        u32x4 vp = *(const u32x4*)(qk + nbase + off + 64);
        const float a = al[e];
        #pragma unroll
        for (int i = 0; i < 4; ++i) {
            o[2*i]   = fmaf(a, blo(vp[i]), o[2*i]);
            o[2*i+1] = fmaf(a, bhi(vp[i]), o[2*i+1]);
        }
    }
    const float r = __fdividef(1.0f, s + 1e-16f);
    u32x4 sp = *(const u32x4*)(qk + nbase + 96);
    u32x4 res;
    #pragma unroll
    for (int i = 0; i < 4; ++i) {
        float h0 = gelu_f(fmaf(o[2*i],   r, blo(sp[i])));
        float h1 = gelu_f(fmaf(o[2*i+1], r, bhi(sp[i])));
        res[i] = packbf(h0, h1);
    }
    *(u32x4*)((u32*)xc + (n << 6) + 32 + l8 * 4) = res;
}

// ---------------- host launcher ----------------
extern "C" void kernel_launch(void* const* d_in, const int* in_sizes, int n_in,
                              void* d_out, int out_size, void* d_ws, size_t ws_size,
                              hipStream_t stream) {
    const float* x   = (const float*)d_in[0];
    const float* cW1 = (const float*)d_in[1];
    const float* cb1 = (const float*)d_in[2];
    const float* cW2 = (const float*)d_in[3];
    const float* cb2 = (const float*)d_in[4];
    const float* q1W = (const float*)d_in[5];
    const float* q1b = (const float*)d_in[6];
    const float* k1W = (const float*)d_in[7];
    const float* k1b = (const float*)d_in[8];
    const float* v1W = (const float*)d_in[9];
    const float* v1b = (const float*)d_in[10];
    const float* s1W = (const float*)d_in[11];
    const float* s1b = (const float*)d_in[12];
    const float* q2W = (const float*)d_in[13];
    const float* q2b = (const float*)d_in[14];
    const float* k2W = (const float*)d_in[15];
    const float* k2b = (const float*)d_in[16];
    const float* v2W = (const float*)d_in[17];
    const float* v2b = (const float*)d_in[18];
    const float* s2W = (const float*)d_in[19];
    const float* s2b = (const float*)d_in[20];
    const float* fW1 = (const float*)d_in[21];
    const float* fb1 = (const float*)d_in[22];
    const float* fW2 = (const float*)d_in[23];
    const float* fb2 = (const float*)d_in[24];

    char* ws = (char*)d_ws;
    float* sig  = (float*)(ws + SIG);
    float* b1   = (float*)(ws + B1OFF);
    float* b2   = (float*)(ws + B2OFF);
    u16* wc1    = (u16*)(ws + WC1);
    u16* wc2    = (u16*)(ws + WC2);
    u16* wf1    = (u16*)(ws + WF1);
    u16* wf2    = (u16*)(ws + WF2);
    u16* wp1    = (u16*)(ws + WP1);
    u16* wp2    = (u16*)(ws + WP2);
    u16* xb     = (u16*)(ws + XB);
    u16* hbuf   = (u16*)(ws + HBUF);
    u16* qkvs2  = (u16*)(ws + QKVS2);
    u16* xc     = (u16*)(ws + XC);
    u16* qkvs1  = (u16*)(ws + QKVS1);
    u16* y1     = (u16*)(ws + Y1);
    u16* tbuf   = (u16*)(ws + TBUF);
    float* gram = (float*)(ws + GRAM);
    float* out  = (float*)d_out;

    gram_kernel<<<160, 256, 0, stream>>>(cW1, cW2, fW1, fW2, gram);
    power_kernel<<<4, 256, 0, stream>>>(gram, sig);
    prep_conv_w<<<dim3(576, 4), 256, 0, stream>>>(cW1, cW2, fW1, fW2, sig,
                                                  wc1, wc2, wf1, wf2);
    prep_proj<<<260, 256, 0, stream>>>(q1W, k1W, v1W, s1W, q2W, k2W, v2W, s2W,
                                       q1b, k1b, v1b, s1b, q2b, k2b, v2b, s2b,
                                       wp1, wp2, b1, b2);
    convert_x<<<1024, 256, 0, stream>>>(x, xb);

    // proj1: [N][64] x [512][64]^T -> qkvs1 [N][512]
    mm_kernel<1, 64, 128, 0><<<dim3(512, 4), 256, 0, stream>>>(
        xb, wp1, b1, qkvs1, 512, 0, 0);
    attn1_kernel<<<NPIX / 16, 256, 0, stream>>>(qkvs1, hbuf);
    // proj2: [N][128] x [256][128]^T -> qkvs2 [N][256]
    mm_kernel<1, 128, 128, 0><<<dim3(512, 2), 256, 0, stream>>>(
        hbuf, wp2, b2, qkvs2, 256, 0, 0);
    attn2_kernel<<<NPIX / 32, 256, 0, stream>>>(qkvs2, xc);

    // conv1: im2col(xb, C=64) x [128][576]^T -> y1 [N][128], gelu
    mm_kernel<9, 64, 128, 0><<<dim3(512, 1), 256, 0, stream>>>(
        xb, wc1, cb1, y1, 128, 0, 1);
    // conv2: im2col(y1, C=128) x [64][1152]^T -> xc cols 0..63, gelu
    mm_kernel<9, 128, 64, 0><<<dim3(512, 1), 256, 0, stream>>>(
        y1, wc2, cb2, xc, 128, 0, 1);
    // conv3: im2col(xc, C=128) x [128][1152]^T -> t [N][128], gelu
    mm_kernel<9, 128, 128, 0><<<dim3(512, 1), 256, 0, stream>>>(
        xc, wf1, fb1, tbuf, 128, 0, 1);
    // conv4: im2col(t, C=128) x [64][1152]^T -> out f32 NCHW, gelu
    mm_kernel<9, 128, 64, 1><<<dim3(512, 1), 256, 0, stream>>>(
        tbuf, wf2, fb2, out, 0, 0, 1);
}